// Round 1
// baseline (33205.777 us; speedup 1.0000x reference)
//
#include <hip/hip_runtime.h>
#include <math.h>

// Problem constants (match setup_inputs in the reference).
#define B_SZ  32
#define T_SZ  400
#define D_SZ  2048
#define S_DEN 2000
#define E_DEN 60000
#define S_NUM 512
#define E_NUM 2048

// One block per (graph, utterance). blocks 0..31: den graph (shared edges),
// blocks 32..63: num graph (per-utterance edges). 1024 threads/block.
// alpha / anew / exp(x-row) live in LDS; edges stream coalesced from L2.
__global__ __launch_bounds__(1024) void chain_fwd_kernel(
    const float* __restrict__ x, const int* __restrict__ lengths,
    const int* __restrict__ den_in, const int* __restrict__ den_out,
    const int* __restrict__ den_pdf, const float* __restrict__ den_prob,
    const float* __restrict__ den_leaky, const float* __restrict__ den_final,
    const int* __restrict__ num_in, const int* __restrict__ num_out,
    const int* __restrict__ num_pdf, const float* __restrict__ num_prob,
    const float* __restrict__ num_leaky, const float* __restrict__ num_final,
    float* __restrict__ part)
{
    __shared__ float xrow[D_SZ];
    __shared__ float alpha[S_DEN];
    __shared__ float anew[S_DEN];
    __shared__ float red[17];

    const int tid  = threadIdx.x;
    const int nthr = 1024;
    const bool is_den = blockIdx.x < B_SZ;
    const int b = blockIdx.x & (B_SZ - 1);

    int S, E;
    const int *e_in, *e_out, *e_pdf;
    const float *e_prob, *leaky, *fin;
    float coeff;
    if (is_den) {
        S = S_DEN; E = E_DEN;
        e_in = den_in; e_out = den_out; e_pdf = den_pdf; e_prob = den_prob;
        leaky = den_leaky; fin = den_final; coeff = 1e-5f;
    } else {
        S = S_NUM; E = E_NUM;
        e_in  = num_in  + b * E_NUM;  e_out = num_out + b * E_NUM;
        e_pdf = num_pdf + b * E_NUM;  e_prob = num_prob + b * E_NUM;
        leaky = num_leaky + b * S_NUM; fin = num_final + b * S_NUM;
        coeff = 1e-20f;
    }

    const int len = lengths[b];
    const float* xb = x + (size_t)b * T_SZ * D_SZ;

    // alpha0: mass 1 on state 0, plus leaky mass.
    for (int s = tid; s < S; s += nthr)
        alpha[s] = coeff * leaky[s] + (s == 0 ? 1.0f : 0.0f);

    float logz = 0.0f;

    for (int t = 0; t < len; ++t) {
        // Phase 0: zero anew, build exp(clip(x[b,t,:])) row in LDS.
        for (int s = tid; s < S; s += nthr) anew[s] = 0.0f;
        const float* xt = xb + (size_t)t * D_SZ;
        for (int d = tid; d < D_SZ; d += nthr) {
            float v = xt[d];
            v = fminf(fmaxf(v, -30.0f), 30.0f);
            xrow[d] = expf(v);
        }
        __syncthreads();

        // Phase 1: edge transitions, scatter-add into anew (LDS atomics).
        for (int e = tid; e < E; e += nthr) {
            float v = alpha[e_in[e]] * e_prob[e] * xrow[e_pdf[e]];
            atomicAdd(&anew[e_out[e]], v);
        }
        __syncthreads();

        // Phase 2: asum = sum(anew) via wave + block reduction.
        float ps = 0.0f;
        for (int s = tid; s < S; s += nthr) ps += anew[s];
        #pragma unroll
        for (int off = 32; off > 0; off >>= 1) ps += __shfl_down(ps, off, 64);
        if ((tid & 63) == 0) red[tid >> 6] = ps;
        __syncthreads();
        if (tid < 64) {
            float v = (tid < (nthr >> 6)) ? red[tid] : 0.0f;
            #pragma unroll
            for (int off = 8; off > 0; off >>= 1) v += __shfl_down(v, off, 64);
            if (tid == 0) red[16] = v;
        }
        __syncthreads();
        const float asum = red[16];
        const float inv  = 1.0f / asum;

        // Phase 3: leaky + renorm, update alpha in place; accrue logz.
        for (int s = tid; s < S; s += nthr)
            alpha[s] = (anew[s] + coeff * leaky[s] * asum) * inv;
        logz += logf(asum);
        __syncthreads();
    }

    // Epilogue: part[block] = logz + log(sum(alpha * final))
    float fs = 0.0f;
    for (int s = tid; s < S; s += nthr) fs += alpha[s] * fin[s];
    #pragma unroll
    for (int off = 32; off > 0; off >>= 1) fs += __shfl_down(fs, off, 64);
    if ((tid & 63) == 0) red[tid >> 6] = fs;
    __syncthreads();
    if (tid < 64) {
        float v = (tid < (nthr >> 6)) ? red[tid] : 0.0f;
        #pragma unroll
        for (int off = 8; off > 0; off >>= 1) v += __shfl_down(v, off, 64);
        if (tid == 0) part[blockIdx.x] = logz + logf(v);
    }
}

// objf = (den_objf - num_objf) / sum(lengths)
__global__ void combine_kernel(const float* __restrict__ part,
                               const int* __restrict__ lengths,
                               float* __restrict__ out)
{
    int tid = threadIdx.x;
    float v = 0.0f, l = 0.0f;
    if (tid < B_SZ) {
        v = part[tid] - part[B_SZ + tid];
        l = (float)lengths[tid];
    }
    #pragma unroll
    for (int off = 32; off > 0; off >>= 1) {
        v += __shfl_down(v, off, 64);
        l += __shfl_down(l, off, 64);
    }
    if (tid == 0) out[0] = v / l;
}

extern "C" void kernel_launch(void* const* d_in, const int* in_sizes, int n_in,
                              void* d_out, int out_size, void* d_ws, size_t ws_size,
                              hipStream_t stream)
{
    const float* x          = (const float*)d_in[0];
    const int*   lengths    = (const int*)  d_in[1];
    const int*   den_in_p   = (const int*)  d_in[2];
    const int*   den_out_p  = (const int*)  d_in[3];
    const int*   den_pdf_p  = (const int*)  d_in[4];
    const float* den_prob_p = (const float*)d_in[5];
    const float* den_leaky  = (const float*)d_in[6];
    const float* den_final  = (const float*)d_in[7];
    const int*   num_in_p   = (const int*)  d_in[8];
    const int*   num_out_p  = (const int*)  d_in[9];
    const int*   num_pdf_p  = (const int*)  d_in[10];
    const float* num_prob_p = (const float*)d_in[11];
    const float* num_leaky  = (const float*)d_in[12];
    const float* num_final  = (const float*)d_in[13];

    float* part = (float*)d_ws;  // [64] per-block log-likelihood partials

    hipLaunchKernelGGL(chain_fwd_kernel, dim3(2 * B_SZ), dim3(1024), 0, stream,
        x, lengths,
        den_in_p, den_out_p, den_pdf_p, den_prob_p, den_leaky, den_final,
        num_in_p, num_out_p, num_pdf_p, num_prob_p, num_leaky, num_final,
        part);

    hipLaunchKernelGGL(combine_kernel, dim3(1), dim3(64), 0, stream,
        part, lengths, (float*)d_out);
}

// Round 2
// 10277.752 us; speedup vs baseline: 3.2308x; 3.2308x over previous
//
#include <hip/hip_runtime.h>
#include <math.h>

// Problem constants (match setup_inputs in the reference).
#define B_SZ   32
#define T_SZ   400
#define D_SZ   2048
#define S_DEN  2000
#define E_DEN  60000
#define S_NUM  512
#define E_NUM  2048
#define DEN_C  1e-5f
#define NUM_C  1e-20f

// Cooperative den pass: 125 blocks x 16 states, plus 32 num blocks.
#define NDEN   125
#define STATES_PER_BLK 16
#define NNUM   B_SZ
#define NBLK   (NDEN + NNUM)
#define NTHR   512

#define XT_SLOTS 8     // rolling transposed-x buffer (2K frames)
#define XT_K     4     // lookahead

// Workspace layout (bytes, all 16-aligned).
#define REC_OFF     0u          // int4[E_DEN] CSR edge records {in,pdf,prob,c*leaky[in]}
#define ROWPTR_OFF  960000u     // int[S_DEN+1]
#define CNT_OFF     968064u     // int[S_DEN] histogram
#define CUR_OFF     976064u     // int[S_DEN] scatter cursors
#define A_OFF       984064u     // float[2][S_DEN*32] alpha double buffer (raw scale)
#define XT_OFF      1496064u    // float[8][D_SZ][32] transposed exp(x)
#define ASUM_OFF    3593216u    // float[3][32]
#define PFIN_OFF    3593600u    // float[3][32]
#define LF_OFF      3593984u    // float: sum(leaky*final) for den
#define TOTD_OFF    3594048u    // float[32]
#define TOTN_OFF    3594176u    // float[32]
#define BAR_OFF     3594304u    // int barrier counter
#define WS_BYTES    3594432u

// ---------------- device-scope grid barrier (den blocks only) ----------------
__device__ __forceinline__ void grid_bar(int* ctr, int target) {
    __syncthreads();
    if (threadIdx.x == 0) {
        __hip_atomic_fetch_add(ctr, 1, __ATOMIC_RELEASE, __HIP_MEMORY_SCOPE_AGENT);
        while (__hip_atomic_load(ctr, __ATOMIC_RELAXED, __HIP_MEMORY_SCOPE_AGENT) < target)
            __builtin_amdgcn_s_sleep(1);
        (void)__hip_atomic_load(ctr, __ATOMIC_ACQUIRE, __HIP_MEMORY_SCOPE_AGENT);
    }
    __syncthreads();
}

// ---------------- prep kernels (run every launch; ws is re-poisoned) --------
__global__ void prep_init(const float* __restrict__ den_leaky,
                          const float* __restrict__ den_final, char* ws) {
    int* cnt = (int*)(ws + CNT_OFF);
    int* cur = (int*)(ws + CUR_OFF);
    float* asum_g = (float*)(ws + ASUM_OFF);
    float* pfin_g = (float*)(ws + PFIN_OFF);
    __shared__ float part[256];
    int tid = threadIdx.x;
    float s = 0.f;
    for (int i = tid; i < S_DEN; i += 256) {
        cnt[i] = 0; cur[i] = 0;
        s += den_leaky[i] * den_final[i];
    }
    part[tid] = s;
    __syncthreads();
    for (int o = 128; o > 0; o >>= 1) { if (tid < o) part[tid] += part[tid + o]; __syncthreads(); }
    if (tid == 0) { *(float*)(ws + LF_OFF) = part[0]; *(int*)(ws + BAR_OFF) = 0; }
    if (tid < 96) { asum_g[tid] = (tid < 32) ? 1.f : 0.f; pfin_g[tid] = 0.f; }
}

__global__ void prep_hist(const int* __restrict__ e_out, char* ws) {
    int e = blockIdx.x * blockDim.x + threadIdx.x;
    if (e < E_DEN) atomicAdd((int*)(ws + CNT_OFF) + e_out[e], 1);
}

__global__ __launch_bounds__(1024) void prep_scan(char* ws) {
    __shared__ int sb[2][2048];
    const int* cnt = (const int*)(ws + CNT_OFF);
    int* rowp = (int*)(ws + ROWPTR_OFF);
    int tid = threadIdx.x;
    for (int i = tid; i < 2048; i += 1024) sb[0][i] = (i < S_DEN) ? cnt[i] : 0;
    __syncthreads();
    int cur = 0;
    for (int d = 1; d < 2048; d <<= 1) {
        for (int i = tid; i < 2048; i += 1024)
            sb[1 - cur][i] = sb[cur][i] + ((i >= d) ? sb[cur][i - d] : 0);
        __syncthreads();
        cur ^= 1;
    }
    if (tid == 0) rowp[0] = 0;
    for (int i = tid; i < S_DEN; i += 1024) rowp[i + 1] = sb[cur][i];
}

__global__ void prep_scatter(const int* __restrict__ e_in, const int* __restrict__ e_out,
                             const int* __restrict__ e_pdf, const float* __restrict__ e_prob,
                             const float* __restrict__ den_leaky, char* ws) {
    int e = blockIdx.x * blockDim.x + threadIdx.x;
    if (e >= E_DEN) return;
    const int* rowp = (const int*)(ws + ROWPTR_OFF);
    int* cur = (int*)(ws + CUR_OFF);
    int4* recs = (int4*)(ws + REC_OFF);
    int o = e_out[e];
    int pos = rowp[o] + atomicAdd(&cur[o], 1);
    int in = e_in[e];
    int4 r;
    r.x = in; r.y = e_pdf[e];
    r.z = __float_as_int(e_prob[e]);
    r.w = __float_as_int(DEN_C * den_leaky[in]);
    recs[pos] = r;
}

// A0 in raw scale WITHOUT leaky: consumed as A0/1 + c*leaky == reference alpha0.
__global__ void prep_a0(char* ws) {
    int i = blockIdx.x * blockDim.x + threadIdx.x;
    if (i >= S_DEN * 32) return;
    ((float*)(ws + A_OFF))[i] = ((i >> 5) == 0) ? 1.f : 0.f;
}

// ---------------- main fused kernel ----------------
__global__ __launch_bounds__(NTHR, 1) void chain_main(
    const float* __restrict__ x, const int* __restrict__ lengths,
    const float* __restrict__ den_final,
    const int* __restrict__ num_in, const int* __restrict__ num_out,
    const int* __restrict__ num_pdf, const float* __restrict__ num_prob,
    const float* __restrict__ num_leaky, const float* __restrict__ num_final,
    char* __restrict__ ws)
{
    __shared__ float smem[3104];
    const int tid = threadIdx.x;
    const int blk = blockIdx.x;

    if (blk < NDEN) {
        // ===================== den: cooperative, b-vectorized =====================
        const int4* __restrict__ recs = (const int4*)(ws + REC_OFF);
        const int*  __restrict__ rowp = (const int*)(ws + ROWPTR_OFF);
        float* __restrict__ Abuf   = (float*)(ws + A_OFF);
        float* __restrict__ xt     = (float*)(ws + XT_OFF);
        float* __restrict__ asum_g = (float*)(ws + ASUM_OFF);
        float* __restrict__ pfin_g = (float*)(ws + PFIN_OFF);
        float* __restrict__ totd   = (float*)(ws + TOTD_OFF);
        int*   __restrict__ bar    = (int*)(ws + BAR_OFF);
        const float LF = *(const float*)(ws + LF_OFF);

        float* tile = smem;          // [32][65] transpose tile
        float* p_as = smem + 2080;   // [32] block partial asum
        float* p_pf = smem + 2112;   // [32] block partial sum(anew*final)
        float* lz   = smem + 2144;   // [32] logz (block 0 only)

        const int s_loc = tid >> 5;
        const int s     = blk * STATES_PER_BLK + s_loc;
        const int b     = tid & 31;
        const int rp0   = rowp[s];
        const int rp1   = rowp[s + 1];
        const float fin_s = den_final[s];
        float* Arow0 = Abuf;
        float* Arow1 = Abuf + S_DEN * 32;
        int len_b = 0;
        if (blk == 0 && tid < 32) { lz[tid] = 0.f; len_b = lengths[tid]; }

        // Initial transpose: frames 0..XT_K-1, blocks 0..31 own d-tile = blk*64.
        if (blk < 32) {
            for (int f = 0; f < XT_K; ++f) {
                {
                    const int j = tid & 63, rg = tid >> 6;
                    for (int bb = rg; bb < 32; bb += 8)
                        tile[bb * 65 + j] = x[((bb * T_SZ) + f) * D_SZ + blk * 64 + j];
                }
                __syncthreads();
                {
                    const int bb = tid & 31, jg = tid >> 5;
                    for (int j = jg; j < 64; j += 16) {
                        float v = fminf(fmaxf(tile[bb * 65 + j], -30.f), 30.f);
                        xt[((f & 7) * D_SZ + blk * 64 + j) * 32 + bb] = __expf(v);
                    }
                }
                __syncthreads();
            }
        }
        int bt = NDEN;
        grid_bar(bar, bt);

        for (int t = 0; t < T_SZ; ++t) {
            const float* Aprev = (t & 1) ? Arow1 : Arow0;
            float*       Anew  = (t & 1) ? Arow0 : Arow1;
            const float* xts   = xt + (size_t)(t & 7) * D_SZ * 32;

            if (tid < 32) p_as[tid] = 0.f;
            else if (tid < 64) p_pf[tid - 32] = 0.f;

            const int f = t + XT_K;
            const bool do_tr = (blk < 32) && (f < T_SZ);
            if (do_tr) {
                const int j = tid & 63, rg = tid >> 6;
                for (int bb = rg; bb < 32; bb += 8)
                    tile[bb * 65 + j] = x[((bb * T_SZ) + f) * D_SZ + blk * 64 + j];
            }
            __syncthreads();
            if (do_tr) {
                const int bb = tid & 31, jg = tid >> 5;
                for (int j = jg; j < 64; j += 16) {
                    float v = fminf(fmaxf(tile[bb * 65 + j], -30.f), 30.f);
                    xt[((f & 7) * D_SZ + blk * 64 + j) * 32 + bb] = __expf(v);
                }
            }

            // Edge phase: fold renorm+leaky into the gather:
            // adash_prev[in] = Araw_prev[in]*inv_asum + c*leaky[in]
            const float inv_as = 1.f / asum_g[(t % 3) * 32 + b];
            float acc = 0.f;
            for (int k = rp0; k < rp1; ++k) {
                int4 r = recs[k];
                float a = __fmaf_rn(Aprev[r.x * 32 + b], inv_as, __int_as_float(r.w));
                acc = __fmaf_rn(a * __int_as_float(r.z), xts[r.y * 32 + b], acc);
            }
            Anew[s * 32 + b] = acc;
            atomicAdd(&p_as[b], acc);
            atomicAdd(&p_pf[b], acc * fin_s);
            __syncthreads();

            const int slot_w = ((t + 1) % 3) * 32;
            if (tid < 32) atomicAdd(&asum_g[slot_w + tid], p_as[tid]);
            else if (tid < 64) atomicAdd(&pfin_g[slot_w + (tid - 32)], p_pf[tid - 32]);
            if (blk == 0) {
                const int slot_z = ((t + 2) % 3) * 32;
                if (tid >= 64 && tid < 96) asum_g[slot_z + (tid - 64)] = 0.f;
                else if (tid >= 96 && tid < 128) pfin_g[slot_z + (tid - 96)] = 0.f;
            }
            bt += NDEN;
            grid_bar(bar, bt);

            if (blk == 0 && tid < 32) {
                const float as = asum_g[slot_w + tid];
                if (t + 1 == len_b) {
                    const float P = pfin_g[slot_w + tid];
                    totd[tid] = lz[tid] + logf(P + DEN_C * LF * as);
                }
                lz[tid] += logf(as);
            }
        }
    } else {
        // ===================== num: one block per utterance, LDS-local ============
        const int b = blk - NDEN;
        float* alpha = smem;          // [512]
        float* anew  = smem + 512;    // [512]
        float* xrow  = smem + 1024;   // [2048]
        float* red   = smem + 3072;   // [9]
        float* totn  = (float*)(ws + TOTN_OFF);

        const int len = lengths[b];
        const float lk = num_leaky[b * S_NUM + tid];
        const float fn = num_final[b * S_NUM + tid];
        const int*   ein  = num_in   + b * E_NUM;
        const int*   eout = num_out  + b * E_NUM;
        const int*   epdf = num_pdf  + b * E_NUM;
        const float* eprb = num_prob + b * E_NUM;
        const float* xb = x + (size_t)b * T_SZ * D_SZ;

        alpha[tid] = NUM_C * lk + (tid == 0 ? 1.f : 0.f);
        float logz = 0.f;
        __syncthreads();

        for (int t = 0; t < len; ++t) {
            anew[tid] = 0.f;
            const float* xp = xb + (size_t)t * D_SZ;
            for (int d = tid; d < D_SZ; d += NTHR)
                xrow[d] = __expf(fminf(fmaxf(xp[d], -30.f), 30.f));
            __syncthreads();
            for (int e = tid; e < E_NUM; e += NTHR) {
                float v = alpha[ein[e]] * eprb[e] * xrow[epdf[e]];
                atomicAdd(&anew[eout[e]], v);
            }
            __syncthreads();
            float ps = anew[tid];
            #pragma unroll
            for (int o = 32; o > 0; o >>= 1) ps += __shfl_down(ps, o, 64);
            if ((tid & 63) == 0) red[tid >> 6] = ps;
            __syncthreads();
            if (tid < 64) {
                float v2 = (tid < 8) ? red[tid] : 0.f;
                #pragma unroll
                for (int o = 4; o > 0; o >>= 1) v2 += __shfl_down(v2, o, 64);
                if (tid == 0) red[8] = v2;
            }
            __syncthreads();
            const float asum = red[8];
            alpha[tid] = __fmaf_rn(NUM_C * lk, asum, anew[tid]) * (1.f / asum);
            logz += logf(asum);
            __syncthreads();
        }
        float fs = alpha[tid] * fn;
        #pragma unroll
        for (int o = 32; o > 0; o >>= 1) fs += __shfl_down(fs, o, 64);
        if ((tid & 63) == 0) red[tid >> 6] = fs;
        __syncthreads();
        if (tid < 64) {
            float v2 = (tid < 8) ? red[tid] : 0.f;
            #pragma unroll
            for (int o = 4; o > 0; o >>= 1) v2 += __shfl_down(v2, o, 64);
            if (tid == 0) totn[b] = logz + logf(v2);
        }
    }
}

__global__ void combine2(const char* __restrict__ ws, const int* __restrict__ lengths,
                         float* __restrict__ out) {
    const float* totd = (const float*)(ws + TOTD_OFF);
    const float* totn = (const float*)(ws + TOTN_OFF);
    int tid = threadIdx.x;
    float v = 0.f, l = 0.f;
    if (tid < B_SZ) { v = totd[tid] - totn[tid]; l = (float)lengths[tid]; }
    #pragma unroll
    for (int o = 32; o > 0; o >>= 1) { v += __shfl_down(v, o, 64); l += __shfl_down(l, o, 64); }
    if (tid == 0) out[0] = v / l;
}

// ===================== round-1 fallback (used only if ws too small) ==========
__global__ __launch_bounds__(1024) void chain_fwd_kernel(
    const float* __restrict__ x, const int* __restrict__ lengths,
    const int* __restrict__ den_in, const int* __restrict__ den_out,
    const int* __restrict__ den_pdf, const float* __restrict__ den_prob,
    const float* __restrict__ den_leaky, const float* __restrict__ den_final,
    const int* __restrict__ num_in, const int* __restrict__ num_out,
    const int* __restrict__ num_pdf, const float* __restrict__ num_prob,
    const float* __restrict__ num_leaky, const float* __restrict__ num_final,
    float* __restrict__ part)
{
    __shared__ float xrow[D_SZ];
    __shared__ float alpha[S_DEN];
    __shared__ float anew[S_DEN];
    __shared__ float red[17];
    const int tid = threadIdx.x;
    const int nthr = 1024;
    const bool is_den = blockIdx.x < B_SZ;
    const int b = blockIdx.x & (B_SZ - 1);
    int S, E;
    const int *e_in, *e_out, *e_pdf;
    const float *e_prob, *leaky, *fin;
    float coeff;
    if (is_den) {
        S = S_DEN; E = E_DEN;
        e_in = den_in; e_out = den_out; e_pdf = den_pdf; e_prob = den_prob;
        leaky = den_leaky; fin = den_final; coeff = DEN_C;
    } else {
        S = S_NUM; E = E_NUM;
        e_in = num_in + b * E_NUM; e_out = num_out + b * E_NUM;
        e_pdf = num_pdf + b * E_NUM; e_prob = num_prob + b * E_NUM;
        leaky = num_leaky + b * S_NUM; fin = num_final + b * S_NUM;
        coeff = NUM_C;
    }
    const int len = lengths[b];
    const float* xb = x + (size_t)b * T_SZ * D_SZ;
    for (int s = tid; s < S; s += nthr)
        alpha[s] = coeff * leaky[s] + (s == 0 ? 1.0f : 0.0f);
    float logz = 0.0f;
    for (int t = 0; t < len; ++t) {
        for (int s = tid; s < S; s += nthr) anew[s] = 0.0f;
        const float* xt = xb + (size_t)t * D_SZ;
        for (int d = tid; d < D_SZ; d += nthr)
            xrow[d] = __expf(fminf(fmaxf(xt[d], -30.0f), 30.0f));
        __syncthreads();
        for (int e = tid; e < E; e += nthr) {
            float v = alpha[e_in[e]] * e_prob[e] * xrow[e_pdf[e]];
            atomicAdd(&anew[e_out[e]], v);
        }
        __syncthreads();
        float ps = 0.0f;
        for (int s = tid; s < S; s += nthr) ps += anew[s];
        #pragma unroll
        for (int off = 32; off > 0; off >>= 1) ps += __shfl_down(ps, off, 64);
        if ((tid & 63) == 0) red[tid >> 6] = ps;
        __syncthreads();
        if (tid < 64) {
            float v = (tid < 16) ? red[tid] : 0.0f;
            #pragma unroll
            for (int off = 8; off > 0; off >>= 1) v += __shfl_down(v, off, 64);
            if (tid == 0) red[16] = v;
        }
        __syncthreads();
        const float asum = red[16];
        const float inv = 1.0f / asum;
        for (int s = tid; s < S; s += nthr)
            alpha[s] = (anew[s] + coeff * leaky[s] * asum) * inv;
        logz += logf(asum);
        __syncthreads();
    }
    float fs = 0.0f;
    for (int s = tid; s < S; s += nthr) fs += alpha[s] * fin[s];
    #pragma unroll
    for (int off = 32; off > 0; off >>= 1) fs += __shfl_down(fs, off, 64);
    if ((tid & 63) == 0) red[tid >> 6] = fs;
    __syncthreads();
    if (tid < 64) {
        float v = (tid < 16) ? red[tid] : 0.0f;
        #pragma unroll
        for (int off = 8; off > 0; off >>= 1) v += __shfl_down(v, off, 64);
        if (tid == 0) part[blockIdx.x] = logz + logf(v);
    }
}

__global__ void combine_kernel(const float* __restrict__ part,
                               const int* __restrict__ lengths,
                               float* __restrict__ out)
{
    int tid = threadIdx.x;
    float v = 0.0f, l = 0.0f;
    if (tid < B_SZ) { v = part[tid] - part[B_SZ + tid]; l = (float)lengths[tid]; }
    #pragma unroll
    for (int off = 32; off > 0; off >>= 1) { v += __shfl_down(v, off, 64); l += __shfl_down(l, off, 64); }
    if (tid == 0) out[0] = v / l;
}

// ---------------------------------------------------------------------------
extern "C" void kernel_launch(void* const* d_in, const int* in_sizes, int n_in,
                              void* d_out, int out_size, void* d_ws, size_t ws_size,
                              hipStream_t stream)
{
    const float* x          = (const float*)d_in[0];
    const int*   lengths    = (const int*)  d_in[1];
    const int*   den_in_p   = (const int*)  d_in[2];
    const int*   den_out_p  = (const int*)  d_in[3];
    const int*   den_pdf_p  = (const int*)  d_in[4];
    const float* den_prob_p = (const float*)d_in[5];
    const float* den_leaky  = (const float*)d_in[6];
    const float* den_final  = (const float*)d_in[7];
    const int*   num_in_p   = (const int*)  d_in[8];
    const int*   num_out_p  = (const int*)  d_in[9];
    const int*   num_pdf_p  = (const int*)  d_in[10];
    const float* num_prob_p = (const float*)d_in[11];
    const float* num_leaky  = (const float*)d_in[12];
    const float* num_final  = (const float*)d_in[13];

    if (ws_size >= WS_BYTES) {
        char* ws = (char*)d_ws;
        hipLaunchKernelGGL(prep_init, dim3(1), dim3(256), 0, stream,
                           den_leaky, den_final, ws);
        hipLaunchKernelGGL(prep_hist, dim3((E_DEN + 255) / 256), dim3(256), 0, stream,
                           den_out_p, ws);
        hipLaunchKernelGGL(prep_scan, dim3(1), dim3(1024), 0, stream, ws);
        hipLaunchKernelGGL(prep_scatter, dim3((E_DEN + 255) / 256), dim3(256), 0, stream,
                           den_in_p, den_out_p, den_pdf_p, den_prob_p, den_leaky, ws);
        hipLaunchKernelGGL(prep_a0, dim3((S_DEN * 32 + 255) / 256), dim3(256), 0, stream, ws);
        hipLaunchKernelGGL(chain_main, dim3(NBLK), dim3(NTHR), 0, stream,
                           x, lengths, den_final,
                           num_in_p, num_out_p, num_pdf_p, num_prob_p,
                           num_leaky, num_final, ws);
        hipLaunchKernelGGL(combine2, dim3(1), dim3(64), 0, stream,
                           ws, lengths, (float*)d_out);
    } else {
        float* part = (float*)d_ws;
        hipLaunchKernelGGL(chain_fwd_kernel, dim3(2 * B_SZ), dim3(1024), 0, stream,
                           x, lengths,
                           den_in_p, den_out_p, den_pdf_p, den_prob_p, den_leaky, den_final,
                           num_in_p, num_out_p, num_pdf_p, num_prob_p, num_leaky, num_final,
                           part);
        hipLaunchKernelGGL(combine_kernel, dim3(1), dim3(64), 0, stream,
                           part, lengths, (float*)d_out);
    }
}

// Round 3
// 7405.743 us; speedup vs baseline: 4.4838x; 1.3878x over previous
//
#include <hip/hip_runtime.h>
#include <math.h>

// Problem constants (match setup_inputs in the reference).
#define B_SZ   32
#define T_SZ   400
#define D_SZ   2048
#define S_DEN  2000
#define E_DEN  60000
#define S_NUM  512
#define E_NUM  2048
#define DEN_C  1e-5f
#define NUM_C  1e-20f

// Grid: 250 edge blocks (8 states x 4 quarters x 32 b = 1024 thr)
//       + 32 transposer blocks + 32 num blocks.
#define NDEN_E 250
#define NT     32
#define NBAR   (NDEN_E + NT)     // blocks participating in the grid barrier
#define NNUM   B_SZ
#define NBLK   (NBAR + NNUM)
#define NTHR   1024

#define XT_K     4     // lookahead frames (8-slot rolling buffer)
#define REC_CAP  768   // LDS record capacity per edge block (mean ~120)

// Workspace layout (bytes, all 16-aligned).
#define REC_OFF     0u          // int4[E_DEN] CSR edge records {in,pdf,prob,c*leaky[in]}
#define ROWPTR_OFF  960000u     // int[S_DEN+1]
#define CNT_OFF     968064u     // int[S_DEN] histogram
#define CUR_OFF     976064u     // int[S_DEN] scatter cursors
#define A_OFF       984064u     // float[2][S_DEN*32] alpha double buffer (raw scale)
#define XT_OFF      1496064u    // float[8][D_SZ][32] transposed exp(x)
#define ASUM_OFF    3593216u    // float[3][32]
#define PFIN_OFF    3593600u    // float[3][32]
#define LF_OFF      3593984u    // float: sum(leaky*final) for den
#define TOTD_OFF    3594048u    // float[32]
#define TOTN_OFF    3594176u    // float[32]
#define BAR_OFF     3594304u    // int barrier counter
#define WS_BYTES    3594432u

// ---------------- device-scope grid barrier ----------------
__device__ __forceinline__ void grid_bar(int* ctr, int target) {
    __syncthreads();
    if (threadIdx.x == 0) {
        __hip_atomic_fetch_add(ctr, 1, __ATOMIC_RELEASE, __HIP_MEMORY_SCOPE_AGENT);
        while (__hip_atomic_load(ctr, __ATOMIC_RELAXED, __HIP_MEMORY_SCOPE_AGENT) < target)
            __builtin_amdgcn_s_sleep(1);
        (void)__hip_atomic_load(ctr, __ATOMIC_ACQUIRE, __HIP_MEMORY_SCOPE_AGENT);
    }
    __syncthreads();
}

// ---------------- prep kernels ----------------
__global__ void prep_init(const float* __restrict__ den_leaky,
                          const float* __restrict__ den_final, char* ws) {
    int* cnt = (int*)(ws + CNT_OFF);
    int* cur = (int*)(ws + CUR_OFF);
    float* asum_g = (float*)(ws + ASUM_OFF);
    float* pfin_g = (float*)(ws + PFIN_OFF);
    __shared__ float part[256];
    int tid = threadIdx.x;
    float s = 0.f;
    for (int i = tid; i < S_DEN; i += 256) {
        cnt[i] = 0; cur[i] = 0;
        s += den_leaky[i] * den_final[i];
    }
    part[tid] = s;
    __syncthreads();
    for (int o = 128; o > 0; o >>= 1) { if (tid < o) part[tid] += part[tid + o]; __syncthreads(); }
    if (tid == 0) { *(float*)(ws + LF_OFF) = part[0]; *(int*)(ws + BAR_OFF) = 0; }
    if (tid < 96) { asum_g[tid] = (tid < 32) ? 1.f : 0.f; pfin_g[tid] = 0.f; }
}

__global__ void prep_hist(const int* __restrict__ e_out, char* ws) {
    int e = blockIdx.x * blockDim.x + threadIdx.x;
    if (e < E_DEN) atomicAdd((int*)(ws + CNT_OFF) + e_out[e], 1);
}

__global__ __launch_bounds__(1024) void prep_scan(char* ws) {
    __shared__ int sb[2][2048];
    const int* cnt = (const int*)(ws + CNT_OFF);
    int* rowp = (int*)(ws + ROWPTR_OFF);
    int tid = threadIdx.x;
    for (int i = tid; i < 2048; i += 1024) sb[0][i] = (i < S_DEN) ? cnt[i] : 0;
    __syncthreads();
    int cur = 0;
    for (int d = 1; d < 2048; d <<= 1) {
        for (int i = tid; i < 2048; i += 1024)
            sb[1 - cur][i] = sb[cur][i] + ((i >= d) ? sb[cur][i - d] : 0);
        __syncthreads();
        cur ^= 1;
    }
    if (tid == 0) rowp[0] = 0;
    for (int i = tid; i < S_DEN; i += 1024) rowp[i + 1] = sb[cur][i];
}

__global__ void prep_scatter(const int* __restrict__ e_in, const int* __restrict__ e_out,
                             const int* __restrict__ e_pdf, const float* __restrict__ e_prob,
                             const float* __restrict__ den_leaky, char* ws) {
    int e = blockIdx.x * blockDim.x + threadIdx.x;
    if (e >= E_DEN) return;
    const int* rowp = (const int*)(ws + ROWPTR_OFF);
    int* cur = (int*)(ws + CUR_OFF);
    int4* recs = (int4*)(ws + REC_OFF);
    int o = e_out[e];
    int pos = rowp[o] + atomicAdd(&cur[o], 1);
    int in = e_in[e];
    int4 r;
    r.x = in; r.y = e_pdf[e];
    r.z = __float_as_int(e_prob[e]);
    r.w = __float_as_int(DEN_C * den_leaky[in]);
    recs[pos] = r;
}

__global__ void prep_a0(char* ws) {
    int i = blockIdx.x * blockDim.x + threadIdx.x;
    if (i >= S_DEN * 32) return;
    ((float*)(ws + A_OFF))[i] = ((i >> 5) == 0) ? 1.f : 0.f;
}

// ---------------- main fused kernel ----------------
__global__ __launch_bounds__(NTHR, 1) void chain_main(
    const float* __restrict__ x, const int* __restrict__ lengths,
    const float* __restrict__ den_final,
    const int* __restrict__ num_in, const int* __restrict__ num_out,
    const int* __restrict__ num_pdf, const float* __restrict__ num_prob,
    const float* __restrict__ num_leaky, const float* __restrict__ num_final,
    char* __restrict__ ws)
{
    __shared__ __align__(16) char smem_raw[13760];
    const int tid = threadIdx.x;
    const int blk = blockIdx.x;

    if (blk < NDEN_E) {
        // ================= den edge blocks: 8 states x 4 quarters x 32 b =========
        const int4* __restrict__ recs = (const int4*)(ws + REC_OFF);
        const int*  __restrict__ rowp = (const int*)(ws + ROWPTR_OFF);
        float* __restrict__ Abuf   = (float*)(ws + A_OFF);
        float* __restrict__ xt     = (float*)(ws + XT_OFF);
        float* __restrict__ asum_g = (float*)(ws + ASUM_OFF);
        float* __restrict__ pfin_g = (float*)(ws + PFIN_OFF);
        float* __restrict__ totd   = (float*)(ws + TOTD_OFF);
        int*   __restrict__ bar    = (int*)(ws + BAR_OFF);
        const float LF = *(const float*)(ws + LF_OFF);

        int4*  lrecs = (int4*)smem_raw;                    // [REC_CAP]
        float* sblk  = (float*)(smem_raw + 12288);         // [8*32] per-state acc
        float* p_as  = (float*)(smem_raw + 13312);         // [32]
        float* p_pf  = (float*)(smem_raw + 13440);         // [32]
        float* lz    = (float*)(smem_raw + 13568);         // [32] (block 0 only)

        const int s_loc = tid >> 7;          // 0..7
        const int s     = blk * 8 + s_loc;
        const int quart = (tid >> 5) & 3;    // 0..3
        const int b     = tid & 31;
        const int base  = rowp[blk * 8];
        const int nrec  = rowp[blk * 8 + 8] - base;
        const int r0    = rowp[s] - base;
        const int r1    = rowp[s + 1] - base;
        const bool fits = (nrec <= REC_CAP);
        // fin for the writer phase (tid<256: state = tid>>5)
        const float fin_w = (tid < 256) ? den_final[blk * 8 + (tid >> 5)] : 0.f;

        float* Arow0 = Abuf;
        float* Arow1 = Abuf + S_DEN * 32;
        int len_b = 0;
        if (blk == 0 && tid < 32) { lz[tid] = 0.f; len_b = lengths[tid]; }

        if (fits)
            for (int i = tid; i < nrec; i += NTHR) lrecs[i] = recs[base + i];

        int bt = NBAR;
        grid_bar(bar, bt);

        for (int t = 0; t < T_SZ; ++t) {
            const float* Aprev = (t & 1) ? Arow1 : Arow0;
            float*       Anew  = (t & 1) ? Arow0 : Arow1;
            const float* xts   = xt + (size_t)(t & 7) * (D_SZ * 32);

            if (tid < 256) sblk[tid] = 0.f;
            else if (tid < 288) p_as[tid - 256] = 0.f;
            else if (tid < 320) p_pf[tid - 288] = 0.f;
            const float inv_as = 1.f / asum_g[(t % 3) * 32 + b];
            __syncthreads();

            float acc = 0.f;
            if (fits) {
                #pragma unroll 4
                for (int k = r0 + quart; k < r1; k += 4) {
                    int4 r = lrecs[k];
                    float a = __fmaf_rn(Aprev[r.x * 32 + b], inv_as, __int_as_float(r.w));
                    acc = __fmaf_rn(a * __int_as_float(r.z), xts[r.y * 32 + b], acc);
                }
            } else {
                #pragma unroll 4
                for (int k = r0 + quart; k < r1; k += 4) {
                    int4 r = recs[base + k];
                    float a = __fmaf_rn(Aprev[r.x * 32 + b], inv_as, __int_as_float(r.w));
                    acc = __fmaf_rn(a * __int_as_float(r.z), xts[r.y * 32 + b], acc);
                }
            }
            // combine quarter pairs within the wave, then across the two waves.
            acc += __shfl_down(acc, 32, 64);
            if ((tid & 63) < 32) atomicAdd(&sblk[s_loc * 32 + b], acc);
            __syncthreads();

            if (tid < 256) {
                const float val = sblk[tid];
                const int   b2  = tid & 31;
                Anew[(blk * 8 + (tid >> 5)) * 32 + b2] = val;
                atomicAdd(&p_as[b2], val);
                atomicAdd(&p_pf[b2], val * fin_w);
            }
            __syncthreads();

            const int slot_w = ((t + 1) % 3) * 32;
            if (tid < 32) atomicAdd(&asum_g[slot_w + tid], p_as[tid]);
            else if (tid < 64) atomicAdd(&pfin_g[slot_w + (tid - 32)], p_pf[tid - 32]);
            if (blk == 0) {
                const int slot_z = ((t + 2) % 3) * 32;
                if (tid >= 64 && tid < 96) asum_g[slot_z + (tid - 64)] = 0.f;
                else if (tid >= 96 && tid < 128) pfin_g[slot_z + (tid - 96)] = 0.f;
            }
            bt += NBAR;
            grid_bar(bar, bt);

            if (blk == 0 && tid < 32) {
                const float as = asum_g[slot_w + tid];
                if (t + 1 == len_b)
                    totd[tid] = lz[tid] + logf(pfin_g[slot_w + tid] + DEN_C * LF * as);
                lz[tid] += logf(as);
            }
        }
    } else if (blk < NBAR) {
        // ================= transposer blocks: 64 d-columns each ==================
        const int tb = blk - NDEN_E;
        const int dt = tb * 64;
        float* tile = (float*)smem_raw;    // [32][65]
        float* xt   = (float*)(ws + XT_OFF);
        int*   bar  = (int*)(ws + BAR_OFF);

        for (int f = 0; f < XT_K; ++f) {
            const int j = tid & 63;
            for (int bb = tid >> 6; bb < 32; bb += 16)
                tile[bb * 65 + j] = x[((size_t)(bb * T_SZ) + f) * D_SZ + dt + j];
            __syncthreads();
            const int bb2 = tid & 31;
            for (int j2 = tid >> 5; j2 < 64; j2 += 32) {
                float v = fminf(fmaxf(tile[bb2 * 65 + j2], -30.f), 30.f);
                xt[((size_t)(f & 7) * D_SZ + dt + j2) * 32 + bb2] = __expf(v);
            }
            __syncthreads();
        }
        int bt = NBAR;
        grid_bar(bar, bt);

        for (int t = 0; t < T_SZ; ++t) {
            const int f = t + XT_K;
            if (f < T_SZ) {
                const int j = tid & 63;
                for (int bb = tid >> 6; bb < 32; bb += 16)
                    tile[bb * 65 + j] = x[((size_t)(bb * T_SZ) + f) * D_SZ + dt + j];
                __syncthreads();
                const int bb2 = tid & 31;
                for (int j2 = tid >> 5; j2 < 64; j2 += 32) {
                    float v = fminf(fmaxf(tile[bb2 * 65 + j2], -30.f), 30.f);
                    xt[((size_t)(f & 7) * D_SZ + dt + j2) * 32 + bb2] = __expf(v);
                }
            }
            bt += NBAR;
            grid_bar(bar, bt);
        }
    } else {
        // ================= num blocks: one per utterance, LDS-local ==============
        const int b = blk - NBAR;
        float* alpha = (float*)smem_raw;   // [512]
        float* anew  = alpha + 512;        // [512]
        float* xrow  = anew + 512;         // [2048]
        float* red   = xrow + 2048;        // [17]
        float* totn  = (float*)(ws + TOTN_OFF);

        const int len = lengths[b];
        const float lk = (tid < S_NUM) ? num_leaky[b * S_NUM + tid] : 0.f;
        const float fn = (tid < S_NUM) ? num_final[b * S_NUM + tid] : 0.f;
        const int*   ein  = num_in   + b * E_NUM;
        const int*   eout = num_out  + b * E_NUM;
        const int*   epdf = num_pdf  + b * E_NUM;
        const float* eprb = num_prob + b * E_NUM;
        const float* xb = x + (size_t)b * T_SZ * D_SZ;

        if (tid < S_NUM) alpha[tid] = NUM_C * lk + (tid == 0 ? 1.f : 0.f);
        float logz = 0.f;
        __syncthreads();

        for (int t = 0; t < len; ++t) {
            if (tid < S_NUM) anew[tid] = 0.f;
            const float* xp = xb + (size_t)t * D_SZ;
            for (int d = tid; d < D_SZ; d += NTHR)
                xrow[d] = __expf(fminf(fmaxf(xp[d], -30.f), 30.f));
            __syncthreads();
            for (int e = tid; e < E_NUM; e += NTHR) {
                float v = alpha[ein[e]] * eprb[e] * xrow[epdf[e]];
                atomicAdd(&anew[eout[e]], v);
            }
            __syncthreads();
            float ps = (tid < S_NUM) ? anew[tid] : 0.f;
            #pragma unroll
            for (int o = 32; o > 0; o >>= 1) ps += __shfl_down(ps, o, 64);
            if ((tid & 63) == 0) red[tid >> 6] = ps;
            __syncthreads();
            if (tid < 64) {
                float v2 = (tid < 16) ? red[tid] : 0.f;
                #pragma unroll
                for (int o = 8; o > 0; o >>= 1) v2 += __shfl_down(v2, o, 64);
                if (tid == 0) red[16] = v2;
            }
            __syncthreads();
            const float asum = red[16];
            if (tid < S_NUM)
                alpha[tid] = __fmaf_rn(NUM_C * lk, asum, anew[tid]) * (1.f / asum);
            logz += logf(asum);
            __syncthreads();
        }
        float fs = (tid < S_NUM) ? alpha[tid] * fn : 0.f;
        #pragma unroll
        for (int o = 32; o > 0; o >>= 1) fs += __shfl_down(fs, o, 64);
        if ((tid & 63) == 0) red[tid >> 6] = fs;
        __syncthreads();
        if (tid < 64) {
            float v2 = (tid < 16) ? red[tid] : 0.f;
            #pragma unroll
            for (int o = 8; o > 0; o >>= 1) v2 += __shfl_down(v2, o, 64);
            if (tid == 0) totn[b] = logz + logf(v2);
        }
    }
}

__global__ void combine2(const char* __restrict__ ws, const int* __restrict__ lengths,
                         float* __restrict__ out) {
    const float* totd = (const float*)(ws + TOTD_OFF);
    const float* totn = (const float*)(ws + TOTN_OFF);
    int tid = threadIdx.x;
    float v = 0.f, l = 0.f;
    if (tid < B_SZ) { v = totd[tid] - totn[tid]; l = (float)lengths[tid]; }
    #pragma unroll
    for (int o = 32; o > 0; o >>= 1) { v += __shfl_down(v, o, 64); l += __shfl_down(l, o, 64); }
    if (tid == 0) out[0] = v / l;
}

// ===================== round-1 fallback (used only if ws too small) ==========
__global__ __launch_bounds__(1024) void chain_fwd_kernel(
    const float* __restrict__ x, const int* __restrict__ lengths,
    const int* __restrict__ den_in, const int* __restrict__ den_out,
    const int* __restrict__ den_pdf, const float* __restrict__ den_prob,
    const float* __restrict__ den_leaky, const float* __restrict__ den_final,
    const int* __restrict__ num_in, const int* __restrict__ num_out,
    const int* __restrict__ num_pdf, const float* __restrict__ num_prob,
    const float* __restrict__ num_leaky, const float* __restrict__ num_final,
    float* __restrict__ part)
{
    __shared__ float xrow[D_SZ];
    __shared__ float alpha[S_DEN];
    __shared__ float anew[S_DEN];
    __shared__ float red[17];
    const int tid = threadIdx.x;
    const int nthr = 1024;
    const bool is_den = blockIdx.x < B_SZ;
    const int b = blockIdx.x & (B_SZ - 1);
    int S, E;
    const int *e_in, *e_out, *e_pdf;
    const float *e_prob, *leaky, *fin;
    float coeff;
    if (is_den) {
        S = S_DEN; E = E_DEN;
        e_in = den_in; e_out = den_out; e_pdf = den_pdf; e_prob = den_prob;
        leaky = den_leaky; fin = den_final; coeff = DEN_C;
    } else {
        S = S_NUM; E = E_NUM;
        e_in = num_in + b * E_NUM; e_out = num_out + b * E_NUM;
        e_pdf = num_pdf + b * E_NUM; e_prob = num_prob + b * E_NUM;
        leaky = num_leaky + b * S_NUM; fin = num_final + b * S_NUM;
        coeff = NUM_C;
    }
    const int len = lengths[b];
    const float* xb = x + (size_t)b * T_SZ * D_SZ;
    for (int s = tid; s < S; s += nthr)
        alpha[s] = coeff * leaky[s] + (s == 0 ? 1.0f : 0.0f);
    float logz = 0.0f;
    for (int t = 0; t < len; ++t) {
        for (int s = tid; s < S; s += nthr) anew[s] = 0.0f;
        const float* xt = xb + (size_t)t * D_SZ;
        for (int d = tid; d < D_SZ; d += nthr)
            xrow[d] = __expf(fminf(fmaxf(xt[d], -30.0f), 30.0f));
        __syncthreads();
        for (int e = tid; e < E; e += nthr) {
            float v = alpha[e_in[e]] * e_prob[e] * xrow[e_pdf[e]];
            atomicAdd(&anew[e_out[e]], v);
        }
        __syncthreads();
        float ps = 0.0f;
        for (int s = tid; s < S; s += nthr) ps += anew[s];
        #pragma unroll
        for (int off = 32; off > 0; off >>= 1) ps += __shfl_down(ps, off, 64);
        if ((tid & 63) == 0) red[tid >> 6] = ps;
        __syncthreads();
        if (tid < 64) {
            float v = (tid < 16) ? red[tid] : 0.0f;
            #pragma unroll
            for (int off = 8; off > 0; off >>= 1) v += __shfl_down(v, off, 64);
            if (tid == 0) red[16] = v;
        }
        __syncthreads();
        const float asum = red[16];
        const float inv = 1.0f / asum;
        for (int s = tid; s < S; s += nthr)
            alpha[s] = (anew[s] + coeff * leaky[s] * asum) * inv;
        logz += logf(asum);
        __syncthreads();
    }
    float fs = 0.0f;
    for (int s = tid; s < S; s += nthr) fs += alpha[s] * fin[s];
    #pragma unroll
    for (int off = 32; off > 0; off >>= 1) fs += __shfl_down(fs, off, 64);
    if ((tid & 63) == 0) red[tid >> 6] = fs;
    __syncthreads();
    if (tid < 64) {
        float v = (tid < 16) ? red[tid] : 0.0f;
        #pragma unroll
        for (int off = 8; off > 0; off >>= 1) v += __shfl_down(v, off, 64);
        if (tid == 0) part[blockIdx.x] = logz + logf(v);
    }
}

__global__ void combine_kernel(const float* __restrict__ part,
                               const int* __restrict__ lengths,
                               float* __restrict__ out)
{
    int tid = threadIdx.x;
    float v = 0.0f, l = 0.0f;
    if (tid < B_SZ) { v = part[tid] - part[B_SZ + tid]; l = (float)lengths[tid]; }
    #pragma unroll
    for (int off = 32; off > 0; off >>= 1) { v += __shfl_down(v, off, 64); l += __shfl_down(l, off, 64); }
    if (tid == 0) out[0] = v / l;
}

// ---------------------------------------------------------------------------
extern "C" void kernel_launch(void* const* d_in, const int* in_sizes, int n_in,
                              void* d_out, int out_size, void* d_ws, size_t ws_size,
                              hipStream_t stream)
{
    const float* x          = (const float*)d_in[0];
    const int*   lengths    = (const int*)  d_in[1];
    const int*   den_in_p   = (const int*)  d_in[2];
    const int*   den_out_p  = (const int*)  d_in[3];
    const int*   den_pdf_p  = (const int*)  d_in[4];
    const float* den_prob_p = (const float*)d_in[5];
    const float* den_leaky  = (const float*)d_in[6];
    const float* den_final  = (const float*)d_in[7];
    const int*   num_in_p   = (const int*)  d_in[8];
    const int*   num_out_p  = (const int*)  d_in[9];
    const int*   num_pdf_p  = (const int*)  d_in[10];
    const float* num_prob_p = (const float*)d_in[11];
    const float* num_leaky  = (const float*)d_in[12];
    const float* num_final  = (const float*)d_in[13];

    if (ws_size >= WS_BYTES) {
        char* ws = (char*)d_ws;
        hipLaunchKernelGGL(prep_init, dim3(1), dim3(256), 0, stream,
                           den_leaky, den_final, ws);
        hipLaunchKernelGGL(prep_hist, dim3((E_DEN + 255) / 256), dim3(256), 0, stream,
                           den_out_p, ws);
        hipLaunchKernelGGL(prep_scan, dim3(1), dim3(1024), 0, stream, ws);
        hipLaunchKernelGGL(prep_scatter, dim3((E_DEN + 255) / 256), dim3(256), 0, stream,
                           den_in_p, den_out_p, den_pdf_p, den_prob_p, den_leaky, ws);
        hipLaunchKernelGGL(prep_a0, dim3((S_DEN * 32 + 255) / 256), dim3(256), 0, stream, ws);
        hipLaunchKernelGGL(chain_main, dim3(NBLK), dim3(NTHR), 0, stream,
                           x, lengths, den_final,
                           num_in_p, num_out_p, num_pdf_p, num_prob_p,
                           num_leaky, num_final, ws);
        hipLaunchKernelGGL(combine2, dim3(1), dim3(64), 0, stream,
                           ws, lengths, (float*)d_out);
    } else {
        float* part = (float*)d_ws;
        hipLaunchKernelGGL(chain_fwd_kernel, dim3(2 * B_SZ), dim3(1024), 0, stream,
                           x, lengths,
                           den_in_p, den_out_p, den_pdf_p, den_prob_p, den_leaky, den_final,
                           num_in_p, num_out_p, num_pdf_p, num_prob_p, num_leaky, num_final,
                           part);
        hipLaunchKernelGGL(combine_kernel, dim3(1), dim3(64), 0, stream,
                           part, lengths, (float*)d_out);
    }
}